// Round 1
// baseline (621.312 us; speedup 1.0000x reference)
//
#include <hip/hip_runtime.h>

#define BATCH 2048
#define HID 1024
#define FFN 4096
#define NEXP 8
#define MAXROWS 5120   // sum ceil(count_e/128)*128 <= 4096 + 8*127 -> round up
#define MTILES 40      // MAXROWS/128

typedef __attribute__((ext_vector_type(8))) short short8;
typedef __attribute__((ext_vector_type(4))) float floatx4;

// fp32 -> bf16 round-to-nearest-even (no NaN handling needed for this data)
static __device__ inline unsigned short f2bf(float f) {
    unsigned int u = __float_as_uint(f);
    unsigned int r = (u + 0x7fffu + ((u >> 16) & 1u)) >> 16;
    return (unsigned short)r;
}

// ---- detect whether expert_indices arrived as int64 (odd 32-bit words all 0)
__global__ void detect_fmt(const int* __restrict__ idx32, int* __restrict__ fmt) {
    int t = blockIdx.x * blockDim.x + threadIdx.x;
    if (t >= BATCH) return;
    if (idx32[2 * t + 1] != 0) atomicOr(fmt, 1);  // fmt==1 -> plain int32
}

static __device__ inline int load_idx(const int* idx32, int flat, int is32) {
    return is32 ? idx32[flat] : idx32[2 * flat];  // int64 little-endian low word
}

__global__ void route_count(const int* __restrict__ idx32, const int* __restrict__ fmt,
                            int* __restrict__ counts) {
    int t = blockIdx.x * blockDim.x + threadIdx.x;
    if (t >= BATCH) return;
    int is32 = fmt[0];
    int e0 = load_idx(idx32, 2 * t, is32);
    int e1 = load_idx(idx32, 2 * t + 1, is32);
    atomicAdd(&counts[e0], 1);
    if (e1 != e0) atomicAdd(&counts[e1], 1);
}

__global__ void prefix_k(const int* __restrict__ counts, int* __restrict__ pbase,
                         int* __restrict__ cursor) {
    if (threadIdx.x == 0) {
        int acc = 0;
        for (int e = 0; e < NEXP; e++) {
            pbase[e] = acc;
            cursor[e] = acc;
            acc += ((counts[e] + 127) >> 7) << 7;  // pad each expert segment to 128
        }
        pbase[NEXP] = acc;
    }
}

// one block per token: claim slot(s), record token id/weight, gather x row -> bf16
__global__ void scatter_gather(const float* __restrict__ x, const float* __restrict__ rw,
                               const int* __restrict__ idx32, const int* __restrict__ fmt,
                               int* __restrict__ cursor, int* __restrict__ tids,
                               float* __restrict__ twt, unsigned short* __restrict__ Apk) {
    __shared__ int s_slot[2];
    __shared__ int s_n;
    int b = blockIdx.x;
    if (threadIdx.x == 0) {
        int is32 = fmt[0];
        int e0 = load_idx(idx32, 2 * b, is32);
        int e1 = load_idx(idx32, 2 * b + 1, is32);
        float w0 = rw[2 * b], w1 = rw[2 * b + 1];
        int n, ee[2];
        float ww[2];
        if (e0 == e1) { n = 1; ee[0] = e0; ww[0] = w0 + w1; }
        else { n = 2; ee[0] = e0; ww[0] = w0; ee[1] = e1; ww[1] = w1; }
        for (int j = 0; j < n; j++) {
            int slot = atomicAdd(&cursor[ee[j]], 1);
            s_slot[j] = slot;
            tids[slot] = b;
            twt[slot] = ww[j];
        }
        s_n = n;
    }
    __syncthreads();
    int n = s_n;
    const float4* src = (const float4*)(x + (size_t)b * HID);
    for (int j = 0; j < n; j++) {
        unsigned short* dst = Apk + (size_t)s_slot[j] * HID;
        #pragma unroll
        for (int r = 0; r < 2; r++) {
            int i = threadIdx.x + r * 128;   // 256 float4 = 1024 floats
            float4 v = src[i];
            union { unsigned short u[4]; uint2 q; } p;
            p.u[0] = f2bf(v.x); p.u[1] = f2bf(v.y);
            p.u[2] = f2bf(v.z); p.u[3] = f2bf(v.w);
            *(uint2*)(dst + i * 4) = p.q;
        }
    }
}

// 128x128 tile, BK=32, 4 waves (2x2), 16x16x32 bf16 MFMA.
// A: packed bf16 rows [padded_rows x KTOT]. B: fp32 expert weights [E][KTOT][NTOT],
// converted to bf16 during LDS staging (transposed to [n][k] in LDS).
// SILU=true : store silu(acc) as bf16 into Hout (GEMM1 -> h activations)
// SILU=false: atomicAdd acc*token_weight into Out[token] (GEMM2 -> combine)
template <int KTOT, int NTOT, bool SILU>
__global__ __launch_bounds__(256, 2) void gemm_moe(
    const unsigned short* __restrict__ Abuf, const float* __restrict__ Wall,
    unsigned short* __restrict__ Hout, float* __restrict__ Out,
    const int* __restrict__ tids, const float* __restrict__ twt,
    const int* __restrict__ counts, const int* __restrict__ pbase) {
    __shared__ __align__(16) unsigned short sA[128][40];  // +8 pad: conflict-free b128 reads
    __shared__ __align__(16) unsigned short sB[128][40];  // stored transposed [n][k]

    int row0 = blockIdx.x * 128;
    int totalp = pbase[NEXP];
    if (row0 >= totalp) return;
    int e = 0;
    while (row0 >= pbase[e + 1]) e++;
    int n0 = blockIdx.y * 128;
    const float* Bw = Wall + (size_t)e * KTOT * NTOT;

    int tid = threadIdx.x;
    int lane = tid & 63, wid = tid >> 6;
    int wm = wid & 1, wn = wid >> 1;
    int quad = lane >> 4, l16 = lane & 15;

    floatx4 acc[4][4];
    #pragma unroll
    for (int i = 0; i < 4; i++)
        #pragma unroll
        for (int j = 0; j < 4; j++) acc[i][j] = (floatx4)0.f;

    for (int k0 = 0; k0 < KTOT; k0 += 32) {
        // stage A: 128 rows x 32 bf16; 512 16B-chunks, 2 per thread
        #pragma unroll
        for (int i = 0; i < 2; i++) {
            int q = tid + i * 256;
            int r = q >> 2, c8 = (q & 3) * 8;
            uint4 v = *(const uint4*)(Abuf + (size_t)(row0 + r) * KTOT + k0 + c8);
            *(uint4*)(&sA[r][c8]) = v;
        }
        // stage B: fp32 [32 x 128] -> bf16 transposed [128][32]
        {
            int k = tid >> 3, n16 = (tid & 7) * 16;
            const float* bp = Bw + (size_t)(k0 + k) * NTOT + n0 + n16;
            #pragma unroll
            for (int j = 0; j < 4; j++) {
                float4 v = *(const float4*)(bp + j * 4);
                sB[n16 + j * 4 + 0][k] = f2bf(v.x);
                sB[n16 + j * 4 + 1][k] = f2bf(v.y);
                sB[n16 + j * 4 + 2][k] = f2bf(v.z);
                sB[n16 + j * 4 + 3][k] = f2bf(v.w);
            }
        }
        __syncthreads();
        short8 af[4], bfr[4];
        #pragma unroll
        for (int mi = 0; mi < 4; mi++)
            af[mi] = *(const short8*)(&sA[wm * 64 + mi * 16 + l16][quad * 8]);
        #pragma unroll
        for (int ni = 0; ni < 4; ni++)
            bfr[ni] = *(const short8*)(&sB[wn * 64 + ni * 16 + l16][quad * 8]);
        #pragma unroll
        for (int mi = 0; mi < 4; mi++)
            #pragma unroll
            for (int ni = 0; ni < 4; ni++)
                acc[mi][ni] = __builtin_amdgcn_mfma_f32_16x16x32_bf16(af[mi], bfr[ni], acc[mi][ni], 0, 0, 0);
        __syncthreads();
    }

    // epilogue: C/D layout col=lane&15, row=quad*4+reg
    int cnt = counts[e], pb = pbase[e];
    #pragma unroll
    for (int mi = 0; mi < 4; mi++) {
        int rbase = row0 + wm * 64 + mi * 16 + quad * 4;
        #pragma unroll
        for (int ni = 0; ni < 4; ni++) {
            int col = n0 + wn * 64 + ni * 16 + l16;
            #pragma unroll
            for (int r = 0; r < 4; r++) {
                float v = acc[mi][ni][r];
                int row = rbase + r;
                if (SILU) {
                    float s = v / (1.f + __expf(-v));
                    Hout[(size_t)row * NTOT + col] = f2bf(s);
                } else {
                    if (row - pb < cnt) {
                        atomicAdd(&Out[(size_t)tids[row] * HID + col], v * twt[row]);
                    }
                }
            }
        }
    }
}

extern "C" void kernel_launch(void* const* d_in, const int* in_sizes, int n_in,
                              void* d_out, int out_size, void* d_ws, size_t ws_size,
                              hipStream_t stream) {
    const float* x = (const float*)d_in[0];
    const float* rw = (const float*)d_in[1];
    const float* w1 = (const float*)d_in[2];
    const float* w2 = (const float*)d_in[3];
    const int* idx32 = (const int*)d_in[4];
    float* out = (float*)d_out;

    char* ws = (char*)d_ws;
    int* counts = (int*)(ws + 0);        // 8
    int* cursor = (int*)(ws + 64);       // 8
    int* pbase  = (int*)(ws + 128);      // 9
    int* fmt    = (int*)(ws + 192);      // 1
    int* tids   = (int*)(ws + 4096);     // MAXROWS
    float* twt  = (float*)(ws + 4096 + MAXROWS * 4);
    unsigned short* Apk  = (unsigned short*)(ws + 65536);                                // MAXROWS x HID bf16
    unsigned short* Hact = (unsigned short*)(ws + 65536 + (size_t)MAXROWS * HID * 2);    // MAXROWS x FFN bf16

    hipMemsetAsync(d_ws, 0, 4096, stream);
    hipMemsetAsync(d_out, 0, (size_t)out_size * sizeof(float), stream);

    detect_fmt<<<(BATCH + 255) / 256, 256, 0, stream>>>(idx32, fmt);
    route_count<<<(BATCH + 255) / 256, 256, 0, stream>>>(idx32, fmt, counts);
    prefix_k<<<1, 64, 0, stream>>>(counts, pbase, cursor);
    scatter_gather<<<BATCH, 128, 0, stream>>>(x, rw, idx32, fmt, cursor, tids, twt, Apk);

    gemm_moe<HID, FFN, true><<<dim3(MTILES, FFN / 128), 256, 0, stream>>>(
        Apk, w1, Hact, nullptr, tids, twt, counts, pbase);
    gemm_moe<FFN, HID, false><<<dim3(MTILES, HID / 128), 256, 0, stream>>>(
        Hact, w2, nullptr, out, tids, twt, counts, pbase);
}

// Round 3
// 598.247 us; speedup vs baseline: 1.0386x; 1.0386x over previous
//
#include <hip/hip_runtime.h>

#define BATCH 2048
#define HID 1024
#define FFN 4096
#define NEXP 8
#define MAXROWS 5120   // sum ceil(count_e/128)*128 <= 4096 + 8*127 -> round up
#define MTILES 40      // MAXROWS/128

typedef __attribute__((ext_vector_type(8))) short short8;
typedef __attribute__((ext_vector_type(4))) float floatx4;

// fp32 -> bf16 round-to-nearest-even
static __device__ inline unsigned short f2bf(float f) {
    unsigned int u = __float_as_uint(f);
    unsigned int r = (u + 0x7fffu + ((u >> 16) & 1u)) >> 16;
    return (unsigned short)r;
}

// ---- detect whether expert_indices arrived as int64 (odd 32-bit words all 0)
__global__ void detect_fmt(const int* __restrict__ idx32, int* __restrict__ fmt) {
    int t = blockIdx.x * blockDim.x + threadIdx.x;
    if (t >= BATCH) return;
    if (idx32[2 * t + 1] != 0) atomicOr(fmt, 1);  // fmt==1 -> plain int32
}

static __device__ inline int load_idx(const int* idx32, int flat, int is32) {
    return is32 ? idx32[flat] : idx32[2 * flat];  // int64 little-endian low word
}

__global__ void route_count(const int* __restrict__ idx32, const int* __restrict__ fmt,
                            int* __restrict__ counts) {
    int t = blockIdx.x * blockDim.x + threadIdx.x;
    if (t >= BATCH) return;
    int is32 = fmt[0];
    int e0 = load_idx(idx32, 2 * t, is32);
    int e1 = load_idx(idx32, 2 * t + 1, is32);
    atomicAdd(&counts[e0], 1);
    if (e1 != e0) atomicAdd(&counts[e1], 1);
}

__global__ void prefix_k(const int* __restrict__ counts, int* __restrict__ pbase,
                         int* __restrict__ cursor) {
    if (threadIdx.x == 0) {
        int acc = 0;
        for (int e = 0; e < NEXP; e++) {
            pbase[e] = acc;
            cursor[e] = acc;
            acc += ((counts[e] + 127) >> 7) << 7;
        }
        pbase[NEXP] = acc;
    }
}

__global__ void scatter_gather(const float* __restrict__ x, const float* __restrict__ rw,
                               const int* __restrict__ idx32, const int* __restrict__ fmt,
                               int* __restrict__ cursor, int* __restrict__ tids,
                               float* __restrict__ twt, unsigned short* __restrict__ Apk) {
    __shared__ int s_slot[2];
    __shared__ int s_n;
    int b = blockIdx.x;
    if (threadIdx.x == 0) {
        int is32 = fmt[0];
        int e0 = load_idx(idx32, 2 * b, is32);
        int e1 = load_idx(idx32, 2 * b + 1, is32);
        float w0 = rw[2 * b], w1 = rw[2 * b + 1];
        int n, ee[2];
        float ww[2];
        if (e0 == e1) { n = 1; ee[0] = e0; ww[0] = w0 + w1; }
        else { n = 2; ee[0] = e0; ww[0] = w0; ee[1] = e1; ww[1] = w1; }
        for (int j = 0; j < n; j++) {
            int slot = atomicAdd(&cursor[ee[j]], 1);
            s_slot[j] = slot;
            tids[slot] = b;
            twt[slot] = ww[j];
        }
        s_n = n;
    }
    __syncthreads();
    int n = s_n;
    const float4* src = (const float4*)(x + (size_t)b * HID);
    for (int j = 0; j < n; j++) {
        unsigned short* dst = Apk + (size_t)s_slot[j] * HID;
        #pragma unroll
        for (int r = 0; r < 2; r++) {
            int i = threadIdx.x + r * 128;
            float4 v = src[i];
            union { unsigned short u[4]; uint2 q; } p;
            p.u[0] = f2bf(v.x); p.u[1] = f2bf(v.y);
            p.u[2] = f2bf(v.z); p.u[3] = f2bf(v.w);
            *(uint2*)(dst + i * 4) = p.q;
        }
    }
}

// zero padding rows of Apk and their tids/twt (defensive: no dependence on ws contents)
__global__ void pad_clear(const int* __restrict__ counts, const int* __restrict__ pbase,
                          int* __restrict__ tids, float* __restrict__ twt,
                          unsigned short* __restrict__ Apk) {
    int e = blockIdx.x;
    int start = pbase[e] + counts[e];
    int end = pbase[e + 1];
    for (int row = start; row < end; row++) {
        if (threadIdx.x == 0) { tids[row] = 0; twt[row] = 0.f; }
        uint4 z = make_uint4(0, 0, 0, 0);
        for (int i = threadIdx.x; i < HID / 8; i += 256)
            ((uint4*)(Apk + (size_t)row * HID))[i] = z;
    }
}

// convert fp32 W[E][K][N] -> bf16 Wt[E][N][K] (transpose via 64x64 LDS tile)
__global__ void conv_transpose(const float* __restrict__ W, unsigned short* __restrict__ Wt,
                               int K, int N) {
    __shared__ unsigned short sT[64][65];
    int e = blockIdx.z;
    int kt = blockIdx.y * 64, nt = blockIdx.x * 64;
    const float* src = W + ((size_t)e * K + kt) * N + nt;
    #pragma unroll
    for (int i = 0; i < 4; i++) {
        int t = threadIdx.x + i * 256;          // 0..1023, 64 rows x 16 float4
        int r = t >> 4, c4 = (t & 15) * 4;
        float4 v = *(const float4*)(src + (size_t)r * N + c4);
        sT[c4 + 0][r] = f2bf(v.x);
        sT[c4 + 1][r] = f2bf(v.y);
        sT[c4 + 2][r] = f2bf(v.z);
        sT[c4 + 3][r] = f2bf(v.w);
    }
    __syncthreads();
    #pragma unroll
    for (int i = 0; i < 2; i++) {
        int u = threadIdx.x + i * 256;          // 0..511, 64 rows x 8 uint4
        int n = u >> 3, k8 = (u & 7) * 8;
        union { unsigned short h[8]; uint4 q; } p;
        #pragma unroll
        for (int j = 0; j < 8; j++) p.h[j] = sT[n][k8 + j];
        *(uint4*)(Wt + ((size_t)e * N + nt + n) * K + kt + k8) = p.q;
    }
}

// 128x128 tile, BK=32, explicit uint4 staging (global->VGPR->LDS), row-major [128][32]
// LDS tiles, ds_read_b128 fragments, 16x16x32 bf16 MFMA.
// A: bf16 [rows][KTOT], Bt: bf16 [E][NTOT][KTOT].
template <int KTOT, int NTOT, bool SILU>
__global__ __launch_bounds__(256, 2) void gemm_exp(
    const unsigned short* __restrict__ Abuf, const unsigned short* __restrict__ Bt,
    unsigned short* __restrict__ Hout, float* __restrict__ Out,
    const int* __restrict__ tids, const float* __restrict__ twt,
    const int* __restrict__ counts, const int* __restrict__ pbase) {
    __shared__ __align__(16) unsigned short sA[128 * 32];
    __shared__ __align__(16) unsigned short sB[128 * 32];

    int row0 = blockIdx.x * 128;
    if (row0 >= pbase[NEXP]) return;
    int e = 0;
    while (row0 >= pbase[e + 1]) e++;
    int n0 = blockIdx.y * 128;
    const unsigned short* Bw = Bt + ((size_t)e * NTOT + n0) * KTOT;

    int tid = threadIdx.x;
    int lane = tid & 63;
    int wid = tid >> 6;
    int wm = wid & 1, wn = wid >> 1;
    int quad = lane >> 4, l16 = lane & 15;

    floatx4 acc[4][4];
    #pragma unroll
    for (int i = 0; i < 4; i++)
        #pragma unroll
        for (int j = 0; j < 4; j++) acc[i][j] = (floatx4)0.f;

    for (int k0 = 0; k0 < KTOT; k0 += 32) {
        // 128 rows x 32 bf16 per tile = 512 chunks of 16B; 2 per thread per buffer
        uint4 va[2], vb[2];
        #pragma unroll
        for (int i = 0; i < 2; i++) {
            int ch = tid + i * 256;
            int r = ch >> 2, c8 = (ch & 3) * 8;
            va[i] = *(const uint4*)(Abuf + (size_t)(row0 + r) * KTOT + k0 + c8);
            vb[i] = *(const uint4*)(Bw + (size_t)r * KTOT + k0 + c8);
        }
        #pragma unroll
        for (int i = 0; i < 2; i++) {
            int ch = tid + i * 256;
            *(uint4*)((char*)sA + ch * 16) = va[i];
            *(uint4*)((char*)sB + ch * 16) = vb[i];
        }
        __syncthreads();
        short8 af[4], bfv[4];
        #pragma unroll
        for (int mi = 0; mi < 4; mi++)
            af[mi] = *(const short8*)(sA + (wm * 64 + mi * 16 + l16) * 32 + quad * 8);
        #pragma unroll
        for (int ni = 0; ni < 4; ni++)
            bfv[ni] = *(const short8*)(sB + (wn * 64 + ni * 16 + l16) * 32 + quad * 8);
        #pragma unroll
        for (int mi = 0; mi < 4; mi++)
            #pragma unroll
            for (int ni = 0; ni < 4; ni++)
                acc[mi][ni] = __builtin_amdgcn_mfma_f32_16x16x32_bf16(af[mi], bfv[ni], acc[mi][ni], 0, 0, 0);
        __syncthreads();
    }

    int cnt = counts[e], pb = pbase[e];
    #pragma unroll
    for (int mi = 0; mi < 4; mi++) {
        int rbase = row0 + wm * 64 + mi * 16 + quad * 4;
        #pragma unroll
        for (int ni = 0; ni < 4; ni++) {
            int col = n0 + wn * 64 + ni * 16 + l16;
            #pragma unroll
            for (int r = 0; r < 4; r++) {
                float v = acc[mi][ni][r];
                int row = rbase + r;
                if (SILU) {
                    float s = v / (1.f + __expf(-v));
                    Hout[(size_t)row * NTOT + col] = f2bf(s);
                } else {
                    if (row - pb < cnt) {
                        int t = tids[row];
                        if (t >= 0 && t < BATCH)  // defensive clamp: never write wild
                            atomicAdd(&Out[(size_t)t * HID + col], v * twt[row]);
                    }
                }
            }
        }
    }
}

// ---------- fallback (round-1 fused-convert GEMM, proven) if ws too small ----------
template <int KTOT, int NTOT, bool SILU>
__global__ __launch_bounds__(256, 2) void gemm_fused(
    const unsigned short* __restrict__ Abuf, const float* __restrict__ Wall,
    unsigned short* __restrict__ Hout, float* __restrict__ Out,
    const int* __restrict__ tids, const float* __restrict__ twt,
    const int* __restrict__ counts, const int* __restrict__ pbase) {
    __shared__ __align__(16) unsigned short sA[128][40];
    __shared__ __align__(16) unsigned short sB[128][40];
    int row0 = blockIdx.x * 128;
    if (row0 >= pbase[NEXP]) return;
    int e = 0;
    while (row0 >= pbase[e + 1]) e++;
    int n0 = blockIdx.y * 128;
    const float* Bw = Wall + (size_t)e * KTOT * NTOT;
    int tid = threadIdx.x;
    int lane = tid & 63, wid = tid >> 6;
    int wm = wid & 1, wn = wid >> 1;
    int quad = lane >> 4, l16 = lane & 15;
    floatx4 acc[4][4];
    #pragma unroll
    for (int i = 0; i < 4; i++)
        #pragma unroll
        for (int j = 0; j < 4; j++) acc[i][j] = (floatx4)0.f;
    for (int k0 = 0; k0 < KTOT; k0 += 32) {
        #pragma unroll
        for (int i = 0; i < 2; i++) {
            int q = tid + i * 256;
            int r = q >> 2, c8 = (q & 3) * 8;
            uint4 v = *(const uint4*)(Abuf + (size_t)(row0 + r) * KTOT + k0 + c8);
            *(uint4*)(&sA[r][c8]) = v;
        }
        {
            int k = tid >> 3, n16 = (tid & 7) * 16;
            const float* bp = Bw + (size_t)(k0 + k) * NTOT + n0 + n16;
            #pragma unroll
            for (int j = 0; j < 4; j++) {
                float4 v = *(const float4*)(bp + j * 4);
                sB[n16 + j * 4 + 0][k] = f2bf(v.x);
                sB[n16 + j * 4 + 1][k] = f2bf(v.y);
                sB[n16 + j * 4 + 2][k] = f2bf(v.z);
                sB[n16 + j * 4 + 3][k] = f2bf(v.w);
            }
        }
        __syncthreads();
        short8 af[4], bfr[4];
        #pragma unroll
        for (int mi = 0; mi < 4; mi++)
            af[mi] = *(const short8*)(&sA[wm * 64 + mi * 16 + l16][quad * 8]);
        #pragma unroll
        for (int ni = 0; ni < 4; ni++)
            bfr[ni] = *(const short8*)(&sB[wn * 64 + ni * 16 + l16][quad * 8]);
        #pragma unroll
        for (int mi = 0; mi < 4; mi++)
            #pragma unroll
            for (int ni = 0; ni < 4; ni++)
                acc[mi][ni] = __builtin_amdgcn_mfma_f32_16x16x32_bf16(af[mi], bfr[ni], acc[mi][ni], 0, 0, 0);
        __syncthreads();
    }
    int cnt = counts[e], pb = pbase[e];
    #pragma unroll
    for (int mi = 0; mi < 4; mi++) {
        int rbase = row0 + wm * 64 + mi * 16 + quad * 4;
        #pragma unroll
        for (int ni = 0; ni < 4; ni++) {
            int col = n0 + wn * 64 + ni * 16 + l16;
            #pragma unroll
            for (int r = 0; r < 4; r++) {
                float v = acc[mi][ni][r];
                int row = rbase + r;
                if (SILU) {
                    float s = v / (1.f + __expf(-v));
                    Hout[(size_t)row * NTOT + col] = f2bf(s);
                } else {
                    if (row - pb < cnt) {
                        int t = tids[row];
                        if (t >= 0 && t < BATCH)
                            atomicAdd(&Out[(size_t)t * HID + col], v * twt[row]);
                    }
                }
            }
        }
    }
}

extern "C" void kernel_launch(void* const* d_in, const int* in_sizes, int n_in,
                              void* d_out, int out_size, void* d_ws, size_t ws_size,
                              hipStream_t stream) {
    const float* x = (const float*)d_in[0];
    const float* rw = (const float*)d_in[1];
    const float* w1 = (const float*)d_in[2];
    const float* w2 = (const float*)d_in[3];
    const int* idx32 = (const int*)d_in[4];
    float* out = (float*)d_out;

    char* ws = (char*)d_ws;
    int* counts = (int*)(ws + 0);
    int* cursor = (int*)(ws + 64);
    int* pbase  = (int*)(ws + 128);
    int* fmt    = (int*)(ws + 192);
    int* tids   = (int*)(ws + 4096);
    float* twt  = (float*)(ws + 4096 + MAXROWS * 4);

    size_t off = 65536;
    unsigned short* Apk  = (unsigned short*)(ws + off);  off += (size_t)MAXROWS * HID * 2;    // 10.5 MB
    unsigned short* Hact = (unsigned short*)(ws + off);  off += (size_t)MAXROWS * FFN * 2;    // 41.9 MB
    unsigned short* w1t  = (unsigned short*)(ws + off);  off += (size_t)NEXP * HID * FFN * 2; // 67.1 MB
    unsigned short* w2t  = (unsigned short*)(ws + off);  off += (size_t)NEXP * FFN * HID * 2; // 67.1 MB
    const bool big = ws_size >= off;   // constant per session -> graph-safe branch

    hipMemsetAsync(d_ws, 0, 4096, stream);
    hipMemsetAsync(d_out, 0, (size_t)out_size * sizeof(float), stream);

    detect_fmt<<<(BATCH + 255) / 256, 256, 0, stream>>>(idx32, fmt);
    route_count<<<(BATCH + 255) / 256, 256, 0, stream>>>(idx32, fmt, counts);
    prefix_k<<<1, 64, 0, stream>>>(counts, pbase, cursor);
    scatter_gather<<<BATCH, 128, 0, stream>>>(x, rw, idx32, fmt, cursor, tids, twt, Apk);
    pad_clear<<<NEXP, 256, 0, stream>>>(counts, pbase, tids, twt, Apk);

    if (big) {
        conv_transpose<<<dim3(FFN / 64, HID / 64, NEXP), 256, 0, stream>>>(w1, w1t, HID, FFN);
        conv_transpose<<<dim3(HID / 64, FFN / 64, NEXP), 256, 0, stream>>>(w2, w2t, FFN, HID);
        gemm_exp<HID, FFN, true><<<dim3(MTILES, FFN / 128), 256, 0, stream>>>(
            Apk, w1t, Hact, nullptr, tids, twt, counts, pbase);
        gemm_exp<FFN, HID, false><<<dim3(MTILES, HID / 128), 256, 0, stream>>>(
            Hact, w2t, nullptr, out, tids, twt, counts, pbase);
    } else {
        gemm_fused<HID, FFN, true><<<dim3(MTILES, FFN / 128), 256, 0, stream>>>(
            Apk, w1, Hact, nullptr, tids, twt, counts, pbase);
        gemm_fused<FFN, HID, false><<<dim3(MTILES, HID / 128), 256, 0, stream>>>(
            Hact, w2, nullptr, out, tids, twt, counts, pbase);
    }
}

// Round 4
// 536.141 us; speedup vs baseline: 1.1589x; 1.1158x over previous
//
#include <hip/hip_runtime.h>

#define BATCH 2048
#define HID 1024
#define FFN 4096
#define NEXP 8
#define MAXROWS 5120   // sum ceil(count_e/128)*128 <= 4096 + 8*127 -> round up
#define MTILES 40      // MAXROWS/128

typedef __attribute__((ext_vector_type(8))) short short8;
typedef __attribute__((ext_vector_type(4))) float floatx4;

// fp32 -> bf16 round-to-nearest-even
static __device__ inline unsigned short f2bf(float f) {
    unsigned int u = __float_as_uint(f);
    unsigned int r = (u + 0x7fffu + ((u >> 16) & 1u)) >> 16;
    return (unsigned short)r;
}

static __device__ inline int load_idx(const int* idx32, int flat, int is32) {
    return is32 ? idx32[flat] : idx32[2 * flat];  // int64 little-endian low word
}

// fused: detect int32/int64 layout, per-expert counts, padded prefix sum.
// Single block => __syncthreads gives the needed global ordering.
__global__ void route_all(const int* __restrict__ idx32, int* __restrict__ fmt,
                          int* __restrict__ counts, int* __restrict__ pbase,
                          int* __restrict__ cursor) {
    __shared__ int s_cnt[NEXP];
    __shared__ int s_fmt;
    int t = threadIdx.x;  // 1024 threads
    if (t < NEXP) s_cnt[t] = 0;
    if (t == 0) s_fmt = 0;
    __syncthreads();
    int bad = 0;
    for (int i = t; i < BATCH; i += 1024)       // odd words of first BATCH values
        if (idx32[2 * i + 1] != 0) bad = 1;     // in-bounds for both layouts
    if (bad) atomicOr(&s_fmt, 1);               // nonzero odd word -> plain int32
    __syncthreads();
    int is32 = s_fmt;
    for (int b = t; b < BATCH; b += 1024) {
        int e0 = load_idx(idx32, 2 * b, is32);
        int e1 = load_idx(idx32, 2 * b + 1, is32);
        atomicAdd(&s_cnt[e0], 1);
        if (e1 != e0) atomicAdd(&s_cnt[e1], 1);
    }
    __syncthreads();
    if (t == 0) {
        fmt[0] = is32;
        int acc = 0;
        for (int e = 0; e < NEXP; e++) {
            counts[e] = s_cnt[e];
            pbase[e] = acc;
            cursor[e] = acc;
            acc += ((s_cnt[e] + 127) >> 7) << 7;
        }
        pbase[NEXP] = acc;
    }
}

__global__ void scatter_gather(const float* __restrict__ x, const float* __restrict__ rw,
                               const int* __restrict__ idx32, const int* __restrict__ fmt,
                               int* __restrict__ cursor, int* __restrict__ tids,
                               float* __restrict__ twt, unsigned short* __restrict__ Apk) {
    __shared__ int s_slot[2];
    __shared__ int s_n;
    int b = blockIdx.x;
    if (threadIdx.x == 0) {
        int is32 = fmt[0];
        int e0 = load_idx(idx32, 2 * b, is32);
        int e1 = load_idx(idx32, 2 * b + 1, is32);
        float w0 = rw[2 * b], w1 = rw[2 * b + 1];
        int n, ee[2];
        float ww[2];
        if (e0 == e1) { n = 1; ee[0] = e0; ww[0] = w0 + w1; }
        else { n = 2; ee[0] = e0; ww[0] = w0; ee[1] = e1; ww[1] = w1; }
        for (int j = 0; j < n; j++) {
            int slot = atomicAdd(&cursor[ee[j]], 1);
            s_slot[j] = slot;
            tids[slot] = b;
            twt[slot] = ww[j];
        }
        s_n = n;
    }
    __syncthreads();
    int n = s_n;
    const float4* src = (const float4*)(x + (size_t)b * HID);
    for (int j = 0; j < n; j++) {
        unsigned short* dst = Apk + (size_t)s_slot[j] * HID;
        #pragma unroll
        for (int r = 0; r < 2; r++) {
            int i = threadIdx.x + r * 128;
            float4 v = src[i];
            union { unsigned short u[4]; uint2 q; } p;
            p.u[0] = f2bf(v.x); p.u[1] = f2bf(v.y);
            p.u[2] = f2bf(v.z); p.u[3] = f2bf(v.w);
            *(uint2*)(dst + i * 4) = p.q;
        }
    }
}

// convert fp32 W[E][K][N] -> bf16 Wt[E][N][K] (transpose via 64x64 LDS tile)
__global__ void conv_transpose(const float* __restrict__ W, unsigned short* __restrict__ Wt,
                               int K, int N) {
    __shared__ unsigned short sT[64][65];
    int e = blockIdx.z;
    int kt = blockIdx.y * 64, nt = blockIdx.x * 64;
    const float* src = W + ((size_t)e * K + kt) * N + nt;
    #pragma unroll
    for (int i = 0; i < 4; i++) {
        int t = threadIdx.x + i * 256;          // 0..1023, 64 rows x 16 float4
        int r = t >> 4, c4 = (t & 15) * 4;
        float4 v = *(const float4*)(src + (size_t)r * N + c4);
        sT[c4 + 0][r] = f2bf(v.x);
        sT[c4 + 1][r] = f2bf(v.y);
        sT[c4 + 2][r] = f2bf(v.z);
        sT[c4 + 3][r] = f2bf(v.w);
    }
    __syncthreads();
    #pragma unroll
    for (int i = 0; i < 2; i++) {
        int u = threadIdx.x + i * 256;          // 0..511, 64 rows x 8 uint4
        int n = u >> 3, k8 = (u & 7) * 8;
        union { unsigned short h[8]; uint4 q; } p;
        #pragma unroll
        for (int j = 0; j < 8; j++) p.h[j] = sT[n][k8 + j];
        *(uint4*)(Wt + ((size_t)e * N + nt + n) * K + kt + k8) = p.q;
    }
}

// Double-buffered 128x128 tile, BK=32, register prefetch of next k-tile, one barrier
// per iteration. A: bf16 [rows][KTOT], Bt: bf16 [E][NTOT][KTOT].
// KSPLIT>1 splits K across blockIdx.z (epilogue must be the atomic path).
template <int KTOT, int NTOT, bool SILU, int KSPLIT>
__global__ __launch_bounds__(256, 2) void gemm_db(
    const unsigned short* __restrict__ Abuf, const unsigned short* __restrict__ Bt,
    unsigned short* __restrict__ Hout, float* __restrict__ Out,
    const int* __restrict__ tids, const float* __restrict__ twt,
    const int* __restrict__ counts, const int* __restrict__ pbase) {
    __shared__ __align__(16) unsigned short sA[2][128 * 32];
    __shared__ __align__(16) unsigned short sB[2][128 * 32];

    int row0 = blockIdx.x * 128;
    if (row0 >= pbase[NEXP]) return;
    int e = 0;
    while (row0 >= pbase[e + 1]) e++;
    int n0 = blockIdx.y * 128;
    constexpr int KCH = KTOT / KSPLIT;
    constexpr int NK = KCH / 32;
    int kb = blockIdx.z * KCH;

    const unsigned short* Aw = Abuf + (size_t)row0 * KTOT + kb;
    const unsigned short* Bw = Bt + ((size_t)e * NTOT + n0) * KTOT + kb;

    int tid = threadIdx.x;
    int lane = tid & 63, wid = tid >> 6;
    int wm = wid & 1, wn = wid >> 1;
    int quad = lane >> 4, l16 = lane & 15;

    // staging: 512 16B-chunks per tile; thread covers chunks tid and tid+256
    int r0 = tid >> 2, c0 = (tid & 3) * 8;
    const size_t aoff0 = (size_t)r0 * KTOT + c0;
    const size_t aoff1 = (size_t)(r0 + 64) * KTOT + c0;
    const int ldso0 = tid * 16, ldso1 = (tid + 256) * 16;

    floatx4 acc[4][4];
    #pragma unroll
    for (int i = 0; i < 4; i++)
        #pragma unroll
        for (int j = 0; j < 4; j++) acc[i][j] = (floatx4)0.f;

    uint4 va0 = *(const uint4*)(Aw + aoff0);
    uint4 va1 = *(const uint4*)(Aw + aoff1);
    uint4 vb0 = *(const uint4*)(Bw + aoff0);
    uint4 vb1 = *(const uint4*)(Bw + aoff1);
    *(uint4*)((char*)sA[0] + ldso0) = va0;
    *(uint4*)((char*)sA[0] + ldso1) = va1;
    *(uint4*)((char*)sB[0] + ldso0) = vb0;
    *(uint4*)((char*)sB[0] + ldso1) = vb1;
    __syncthreads();

    for (int k = 0;; k++) {
        int cur = k & 1;
        bool more = (k + 1 < NK);
        if (more) {
            const unsigned short* Ak = Aw + (k + 1) * 32;
            const unsigned short* Bk = Bw + (k + 1) * 32;
            va0 = *(const uint4*)(Ak + aoff0);
            va1 = *(const uint4*)(Ak + aoff1);
            vb0 = *(const uint4*)(Bk + aoff0);
            vb1 = *(const uint4*)(Bk + aoff1);
        }
        short8 af[4], bfv[4];
        #pragma unroll
        for (int mi = 0; mi < 4; mi++)
            af[mi] = *(const short8*)(sA[cur] + (wm * 64 + mi * 16 + l16) * 32 + quad * 8);
        #pragma unroll
        for (int ni = 0; ni < 4; ni++)
            bfv[ni] = *(const short8*)(sB[cur] + (wn * 64 + ni * 16 + l16) * 32 + quad * 8);
        #pragma unroll
        for (int mi = 0; mi < 4; mi++)
            #pragma unroll
            for (int ni = 0; ni < 4; ni++)
                acc[mi][ni] = __builtin_amdgcn_mfma_f32_16x16x32_bf16(af[mi], bfv[ni], acc[mi][ni], 0, 0, 0);
        if (!more) break;
        int nxt = cur ^ 1;
        *(uint4*)((char*)sA[nxt] + ldso0) = va0;
        *(uint4*)((char*)sA[nxt] + ldso1) = va1;
        *(uint4*)((char*)sB[nxt] + ldso0) = vb0;
        *(uint4*)((char*)sB[nxt] + ldso1) = vb1;
        __syncthreads();
    }

    int cnt = counts[e], pb = pbase[e];
    #pragma unroll
    for (int mi = 0; mi < 4; mi++) {
        int rbase = row0 + wm * 64 + mi * 16 + quad * 4;
        #pragma unroll
        for (int ni = 0; ni < 4; ni++) {
            int col = n0 + wn * 64 + ni * 16 + l16;
            #pragma unroll
            for (int r = 0; r < 4; r++) {
                float v = acc[mi][ni][r];
                int row = rbase + r;
                if (SILU) {
                    float s = v / (1.f + __expf(-v));
                    Hout[(size_t)row * NTOT + col] = f2bf(s);
                } else {
                    if (row - pb < cnt) {
                        int t = tids[row];
                        if (t >= 0 && t < BATCH)
                            atomicAdd(&Out[(size_t)t * HID + col], v * twt[row]);
                    }
                }
            }
        }
    }
}

// ---------- fallback (fused-convert GEMM, proven) if ws too small ----------
template <int KTOT, int NTOT, bool SILU>
__global__ __launch_bounds__(256, 2) void gemm_fused(
    const unsigned short* __restrict__ Abuf, const float* __restrict__ Wall,
    unsigned short* __restrict__ Hout, float* __restrict__ Out,
    const int* __restrict__ tids, const float* __restrict__ twt,
    const int* __restrict__ counts, const int* __restrict__ pbase) {
    __shared__ __align__(16) unsigned short sA[128][40];
    __shared__ __align__(16) unsigned short sB[128][40];
    int row0 = blockIdx.x * 128;
    if (row0 >= pbase[NEXP]) return;
    int e = 0;
    while (row0 >= pbase[e + 1]) e++;
    int n0 = blockIdx.y * 128;
    const float* Bw = Wall + (size_t)e * KTOT * NTOT;
    int tid = threadIdx.x;
    int lane = tid & 63, wid = tid >> 6;
    int wm = wid & 1, wn = wid >> 1;
    int quad = lane >> 4, l16 = lane & 15;
    floatx4 acc[4][4];
    #pragma unroll
    for (int i = 0; i < 4; i++)
        #pragma unroll
        for (int j = 0; j < 4; j++) acc[i][j] = (floatx4)0.f;
    for (int k0 = 0; k0 < KTOT; k0 += 32) {
        #pragma unroll
        for (int i = 0; i < 2; i++) {
            int q = tid + i * 256;
            int r = q >> 2, c8 = (q & 3) * 8;
            uint4 v = *(const uint4*)(Abuf + (size_t)(row0 + r) * KTOT + k0 + c8);
            *(uint4*)(&sA[r][c8]) = v;
        }
        {
            int k = tid >> 3, n16 = (tid & 7) * 16;
            const float* bp = Bw + (size_t)(k0 + k) * NTOT + n0 + n16;
            #pragma unroll
            for (int j = 0; j < 4; j++) {
                float4 v = *(const float4*)(bp + j * 4);
                sB[n16 + j * 4 + 0][k] = f2bf(v.x);
                sB[n16 + j * 4 + 1][k] = f2bf(v.y);
                sB[n16 + j * 4 + 2][k] = f2bf(v.z);
                sB[n16 + j * 4 + 3][k] = f2bf(v.w);
            }
        }
        __syncthreads();
        short8 af[4], bfr[4];
        #pragma unroll
        for (int mi = 0; mi < 4; mi++)
            af[mi] = *(const short8*)(&sA[wm * 64 + mi * 16 + l16][quad * 8]);
        #pragma unroll
        for (int ni = 0; ni < 4; ni++)
            bfr[ni] = *(const short8*)(&sB[wn * 64 + ni * 16 + l16][quad * 8]);
        #pragma unroll
        for (int mi = 0; mi < 4; mi++)
            #pragma unroll
            for (int ni = 0; ni < 4; ni++)
                acc[mi][ni] = __builtin_amdgcn_mfma_f32_16x16x32_bf16(af[mi], bfr[ni], acc[mi][ni], 0, 0, 0);
        __syncthreads();
    }
    int cnt = counts[e], pb = pbase[e];
    #pragma unroll
    for (int mi = 0; mi < 4; mi++) {
        int rbase = row0 + wm * 64 + mi * 16 + quad * 4;
        #pragma unroll
        for (int ni = 0; ni < 4; ni++) {
            int col = n0 + wn * 64 + ni * 16 + l16;
            #pragma unroll
            for (int r = 0; r < 4; r++) {
                float v = acc[mi][ni][r];
                int row = rbase + r;
                if (SILU) {
                    float s = v / (1.f + __expf(-v));
                    Hout[(size_t)row * NTOT + col] = f2bf(s);
                } else {
                    if (row - pb < cnt) {
                        int t = tids[row];
                        if (t >= 0 && t < BATCH)
                            atomicAdd(&Out[(size_t)t * HID + col], v * twt[row]);
                    }
                }
            }
        }
    }
}

extern "C" void kernel_launch(void* const* d_in, const int* in_sizes, int n_in,
                              void* d_out, int out_size, void* d_ws, size_t ws_size,
                              hipStream_t stream) {
    const float* x = (const float*)d_in[0];
    const float* rw = (const float*)d_in[1];
    const float* w1 = (const float*)d_in[2];
    const float* w2 = (const float*)d_in[3];
    const int* idx32 = (const int*)d_in[4];
    float* out = (float*)d_out;

    char* ws = (char*)d_ws;
    int* counts = (int*)(ws + 0);
    int* cursor = (int*)(ws + 64);
    int* pbase  = (int*)(ws + 128);
    int* fmt    = (int*)(ws + 192);
    int* tids   = (int*)(ws + 4096);
    float* twt  = (float*)(ws + 4096 + MAXROWS * 4);

    size_t off = 65536;
    unsigned short* Apk  = (unsigned short*)(ws + off);  off += (size_t)MAXROWS * HID * 2;    // 10.5 MB
    unsigned short* Hact = (unsigned short*)(ws + off);  off += (size_t)MAXROWS * FFN * 2;    // 41.9 MB
    unsigned short* w1t  = (unsigned short*)(ws + off);  off += (size_t)NEXP * HID * FFN * 2; // 67.1 MB
    unsigned short* w2t  = (unsigned short*)(ws + off);  off += (size_t)NEXP * FFN * HID * 2; // 67.1 MB
    const bool big = ws_size >= off;   // constant per session -> graph-safe branch

    // zero meta + tids/twt + Apk in one shot (padding rows become true zeros)
    hipMemsetAsync(d_ws, 0, 65536 + (size_t)MAXROWS * HID * 2, stream);
    hipMemsetAsync(d_out, 0, (size_t)out_size * sizeof(float), stream);

    route_all<<<1, 1024, 0, stream>>>(idx32, fmt, counts, pbase, cursor);
    scatter_gather<<<BATCH, 128, 0, stream>>>(x, rw, idx32, fmt, cursor, tids, twt, Apk);

    if (big) {
        conv_transpose<<<dim3(FFN / 64, HID / 64, NEXP), 256, 0, stream>>>(w1, w1t, HID, FFN);
        conv_transpose<<<dim3(HID / 64, FFN / 64, NEXP), 256, 0, stream>>>(w2, w2t, FFN, HID);
        gemm_db<HID, FFN, true, 1><<<dim3(MTILES, FFN / 128, 1), 256, 0, stream>>>(
            Apk, w1t, Hact, nullptr, tids, twt, counts, pbase);
        gemm_db<FFN, HID, false, 4><<<dim3(MTILES, HID / 128, 4), 256, 0, stream>>>(
            Hact, w2t, nullptr, out, tids, twt, counts, pbase);
    } else {
        gemm_fused<HID, FFN, true><<<dim3(MTILES, FFN / 128), 256, 0, stream>>>(
            Apk, w1, Hact, nullptr, tids, twt, counts, pbase);
        gemm_fused<FFN, HID, false><<<dim3(MTILES, HID / 128), 256, 0, stream>>>(
            Hact, w2, nullptr, out, tids, twt, counts, pbase);
    }
}